// Round 1
// baseline (914.890 us; speedup 1.0000x reference)
//
#include <hip/hip_runtime.h>
#include <math.h>

#define AVGD 2.833213344056216f  // log(17.0)

// ---------------- histogram ----------------
__global__ void k_hist(const int* __restrict__ dst, int* __restrict__ deg, int E) {
  int i = blockIdx.x * blockDim.x + threadIdx.x;
  int st = gridDim.x * blockDim.x;
  for (; i < E; i += st) atomicAdd(&deg[dst[i]], 1);
}

// ---------------- scan (3 kernels), CHUNK = 2048 = 256 threads x 8 ----------------
__global__ void k_scan_local(const int* __restrict__ deg, int* __restrict__ off,
                             int* __restrict__ chunkSum, int N) {
  __shared__ int lds[256];
  int t = threadIdx.x;
  int base = blockIdx.x * 2048 + t * 8;
  int v[8];
  int tsum = 0;
#pragma unroll
  for (int i = 0; i < 8; ++i) {
    int idx = base + i;
    v[i] = (idx < N) ? deg[idx] : 0;
    tsum += v[i];
  }
  lds[t] = tsum;
  __syncthreads();
  for (int ofs = 1; ofs < 256; ofs <<= 1) {
    int x = (t >= ofs) ? lds[t - ofs] : 0;
    __syncthreads();
    lds[t] += x;
    __syncthreads();
  }
  int incl = lds[t];
  int run = incl - tsum;  // exclusive prefix of this thread
#pragma unroll
  for (int i = 0; i < 8; ++i) {
    int idx = base + i;
    if (idx < N) off[idx] = run;
    run += v[i];
  }
  if (t == 255) chunkSum[blockIdx.x] = incl;
}

__global__ void k_scan_chunks(const int* __restrict__ chunkSum, int* __restrict__ chunkOff,
                              int nC, int* __restrict__ off, int N) {
  if (threadIdx.x == 0) {
    int run = 0;
    for (int i = 0; i < nC; ++i) { int s = chunkSum[i]; chunkOff[i] = run; run += s; }
    off[N] = run;  // == E
  }
}

__global__ void k_scan_add(int* __restrict__ off, int* __restrict__ cursor,
                           const int* __restrict__ chunkOff, int N) {
  int t = threadIdx.x;
  int base = blockIdx.x * 2048 + t * 8;
  int add = chunkOff[blockIdx.x];
#pragma unroll
  for (int i = 0; i < 8; ++i) {
    int idx = base + i;
    if (idx < N) {
      int v = off[idx] + add;
      off[idx] = v;
      cursor[idx] = v;
    }
  }
}

// ---------------- scatter edges into CSR order, carrying src[e] ----------------
__global__ void k_scatter(const int* __restrict__ dst, const int* __restrict__ src,
                          int* __restrict__ cursor, int2* __restrict__ elist, int E) {
  int i = blockIdx.x * blockDim.x + threadIdx.x;
  int st = gridDim.x * blockDim.x;
  for (; i < E; i += st) {
    int d = dst[i];
    int p = atomicAdd(&cursor[d], 1);
    elist[p] = make_int2(i, src[i]);
  }
}

// ---------------- the big one: per-node multi-stat aggregation ----------------
// One wave per node; lane = feature. ef rows read exactly once (coalesced 256B).
__global__ __launch_bounds__(256) void k_agg(
    const float* __restrict__ h, const float* __restrict__ ef, const float* __restrict__ norm,
    const int2* __restrict__ elist, const int* __restrict__ off, float* __restrict__ ht, int N) {
  int node = (int)((blockIdx.x * 256u + threadIdx.x) >> 6);
  int lane = threadIdx.x & 63;
  if (node >= N) return;
  int beg = off[node], end = off[node + 1];
  float ho = h[(size_t)node * 64 + lane] * norm[node];  // h_in[node]
  float s = 0.f, q = 0.f, mx = -INFINITY, mn = INFINITY;
  for (int cbeg = beg; cbeg < end; cbeg += 64) {
    int cnt = min(64, end - cbeg);
    // cooperative load of up to 64 edge records, broadcast via shfl ->
    // no per-iteration pointer chase; gathers pipeline across iterations.
    int2 my = (lane < cnt) ? elist[cbeg + lane] : make_int2(0, 0);
#pragma unroll 4
    for (int k = 0; k < cnt; ++k) {
      int e = __shfl(my.x, k);
      int sn = __shfl(my.y, k);
      float z = h[(size_t)sn * 64 + lane] * norm[sn] + ho + ef[(size_t)e * 64 + lane];
      s += z;
      q += z * z;
      mx = fmaxf(mx, z);
      mn = fminf(mn, z);
    }
  }
  float degf = (float)(end - beg);
  float mean = s / degf;
  float var = fmaxf(0.f, q / degf - mean * mean);
  float sd = sqrtf(var + 1e-5f);
  float ld = logf(degf + 1.f);
  float scl = 1.f + ld * (1.f / AVGD) + AVGD / ld;  // 1 + logd/AVG + AVG/logd
  // ht = mean over 13 chunks: (h_in + (mean+mx+mn+std)*scl) / 13
  ht[(size_t)node * 64 + lane] = (ho + (mean + mx + mn + sd) * scl) * (1.f / 13.f);
}

// ---------------- column stats (double accumulation) ----------------
__global__ __launch_bounds__(256) void k_colstats(const float* __restrict__ x,
                                                  double* __restrict__ gsum,
                                                  double* __restrict__ gsq, int N) {
  int lane = threadIdx.x & 63;
  int sub = threadIdx.x >> 6;
  int row = blockIdx.x * 4 + sub;
  int stride = gridDim.x * 4;
  double s = 0.0, q = 0.0;
  for (; row < N; row += stride) {
    float v = x[(size_t)row * 64 + lane];
    s += v;
    q += (double)v * (double)v;
  }
  __shared__ double ls[256], lq[256];
  ls[threadIdx.x] = s;
  lq[threadIdx.x] = q;
  __syncthreads();
  if (threadIdx.x < 64) {
    double ss = ls[threadIdx.x] + ls[threadIdx.x + 64] + ls[threadIdx.x + 128] + ls[threadIdx.x + 192];
    double qq = lq[threadIdx.x] + lq[threadIdx.x + 64] + lq[threadIdx.x + 128] + lq[threadIdx.x + 192];
    atomicAdd(&gsum[lane], ss);
    atomicAdd(&gsq[lane], qq);
  }
}

// fold BN (training-mode, biased var) into per-column scale/bias
__global__ void k_finalize(const double* __restrict__ gsum, const double* __restrict__ gsq,
                           const float* __restrict__ g, const float* __restrict__ b,
                           float* __restrict__ scale, float* __restrict__ bias, int N) {
  int d = threadIdx.x;
  if (d >= 64) return;
  double m = gsum[d] / (double)N;
  double v = gsq[d] / (double)N - m * m;
  if (v < 0.0) v = 0.0;
  double istd = 1.0 / sqrt(v + 1e-5);
  double sg = istd * (double)g[d];
  scale[d] = (float)sg;
  bias[d] = (float)((double)b[d] - m * sg);
}

// BN1 apply * norm -> relu -> write r, accumulate BN2 stats in same pass
__global__ __launch_bounds__(256) void k_bnrelu(
    const float* __restrict__ ht, const float* __restrict__ norm,
    const float* __restrict__ scale1, const float* __restrict__ bias1,
    float* __restrict__ r, double* __restrict__ gsum2, double* __restrict__ gsq2, int N) {
  int lane = threadIdx.x & 63;
  int sub = threadIdx.x >> 6;
  float sc = scale1[lane], bi = bias1[lane];
  int row = blockIdx.x * 4 + sub;
  int stride = gridDim.x * 4;
  double s = 0.0, q = 0.0;
  for (; row < N; row += stride) {
    float v = ht[(size_t)row * 64 + lane];
    float rv = fmaxf(0.f, (v * sc + bi) * norm[row]);
    r[(size_t)row * 64 + lane] = rv;
    s += rv;
    q += (double)rv * (double)rv;
  }
  __shared__ double ls[256], lq[256];
  ls[threadIdx.x] = s;
  lq[threadIdx.x] = q;
  __syncthreads();
  if (threadIdx.x < 64) {
    double ss = ls[threadIdx.x] + ls[threadIdx.x + 64] + ls[threadIdx.x + 128] + ls[threadIdx.x + 192];
    double qq = lq[threadIdx.x] + lq[threadIdx.x + 64] + lq[threadIdx.x + 128] + lq[threadIdx.x + 192];
    atomicAdd(&gsum2[lane], ss);
    atomicAdd(&gsq2[lane], qq);
  }
}

// final BN2 apply, float4 vectorized
__global__ void k_out(const float* __restrict__ r, const float* __restrict__ scale2,
                      const float* __restrict__ bias2, float* __restrict__ out, int total4) {
  int i = blockIdx.x * blockDim.x + threadIdx.x;
  if (i >= total4) return;
  float4 v = ((const float4*)r)[i];
  float4 sc = ((const float4*)scale2)[i & 15];
  float4 bb = ((const float4*)bias2)[i & 15];
  float4 o;
  o.x = v.x * sc.x + bb.x;
  o.y = v.y * sc.y + bb.y;
  o.z = v.z * sc.z + bb.z;
  o.w = v.w * sc.w + bb.w;
  ((float4*)out)[i] = o;
}

extern "C" void kernel_launch(void* const* d_in, const int* in_sizes, int n_in,
                              void* d_out, int out_size, void* d_ws, size_t ws_size,
                              hipStream_t stream) {
  const float* h = (const float*)d_in[0];
  const float* ef = (const float*)d_in[1];
  const float* norm = (const float*)d_in[2];
  const float* g1 = (const float*)d_in[3];
  const float* b1 = (const float*)d_in[4];
  const float* g2 = (const float*)d_in[5];
  const float* b2 = (const float*)d_in[6];
  const int* src = (const int*)d_in[7];
  const int* dst = (const int*)d_in[8];
  const int N = in_sizes[2];       // norm is [N,1]
  const int E = in_sizes[8];       // dst is [E]
  float* out = (float*)d_out;

  // workspace carve-up (256B aligned)
  char* ws = (char*)d_ws;
  size_t o = 0;
  auto alloc = [&](size_t bytes) -> void* {
    void* p = ws + o;
    o += (bytes + 255) & ~(size_t)255;
    return p;
  };
  float* ht = (float*)alloc((size_t)N * 64 * 4);
  float* rbuf = (float*)alloc((size_t)N * 64 * 4);
  int2* elist = (int2*)alloc((size_t)E * 8);
  int* off = (int*)alloc((size_t)(N + 1) * 4);
  int* cursor = (int*)alloc((size_t)N * 4);
  int* deg = (int*)alloc((size_t)N * 4);
  const int nC = (N + 2047) / 2048;
  int* chunkSum = (int*)alloc((size_t)nC * 4);
  int* chunkOff = (int*)alloc((size_t)nC * 4);
  double* gsum1 = (double*)alloc(4 * 64 * 8);  // gsum1,gsq1,gsum2,gsq2 contiguous
  double* gsq1 = gsum1 + 64;
  double* gsum2 = gsum1 + 128;
  double* gsq2 = gsum1 + 192;
  float* sc1 = (float*)alloc(4 * 64 * 4);      // sc1,bi1,sc2,bi2 contiguous
  float* bi1 = sc1 + 64;
  float* sc2 = sc1 + 128;
  float* bi2 = sc1 + 192;

  // zero what must be zero each call (ws is poisoned 0xAA before every launch)
  hipMemsetAsync(deg, 0, (size_t)N * 4, stream);
  hipMemsetAsync(gsum1, 0, 4 * 64 * 8, stream);

  k_hist<<<2048, 256, 0, stream>>>(dst, deg, E);
  k_scan_local<<<nC, 256, 0, stream>>>(deg, off, chunkSum, N);
  k_scan_chunks<<<1, 64, 0, stream>>>(chunkSum, chunkOff, nC, off, N);
  k_scan_add<<<nC, 256, 0, stream>>>(off, cursor, chunkOff, N);
  k_scatter<<<2048, 256, 0, stream>>>(dst, src, cursor, elist, E);
  k_agg<<<(N + 3) / 4, 256, 0, stream>>>(h, ef, norm, elist, off, ht, N);
  k_colstats<<<512, 256, 0, stream>>>(ht, gsum1, gsq1, N);
  k_finalize<<<1, 64, 0, stream>>>(gsum1, gsq1, g1, b1, sc1, bi1, N);
  k_bnrelu<<<512, 256, 0, stream>>>(ht, norm, sc1, bi1, rbuf, gsum2, gsq2, N);
  k_finalize<<<1, 64, 0, stream>>>(gsum2, gsq2, g2, b2, sc2, bi2, N);
  k_out<<<(N * 16 + 255) / 256, 256, 0, stream>>>(rbuf, sc2, bi2, out, N * 16);
}